// Round 13
// baseline (151.550 us; speedup 1.0000x reference)
//
#include <hip/hip_runtime.h>
#include <hip/hip_bf16.h>
#include <hip/hip_cooperative_groups.h>
#include <stdint.h>

namespace cg = cooperative_groups;

namespace {
constexpr int Bb   = 8;
constexpr int Ff   = 64;
constexpr int Ee   = 49152;
constexpr int Vv   = 16384;
constexpr int TWOE = 2 * Ee;      // 98304
constexpr int MID  = 96;
constexpr int OUTC = 64;
constexpr int PBLK = 384;         // 384*256 == TWOE; 2/CU guaranteed -> co-residency slack
}

typedef __attribute__((ext_vector_type(8))) short bf16x8;
typedef __attribute__((ext_vector_type(4))) float f32x4;
typedef __attribute__((ext_vector_type(4))) unsigned int u32x4;

// ---------- cooperative prologue: prep -> bucket -> sort in ONE dispatch ----------
__global__ __launch_bounds__(256, 2) void prologue_coop(
    const float* __restrict__ W1, const float* __restrict__ W2,
    const int* __restrict__ conn,
    __hip_bfloat16* __restrict__ w1f, __hip_bfloat16* __restrict__ w2f,
    int* __restrict__ cnt, int* __restrict__ buckets, int* __restrict__ dest)
{
    cg::grid_group grid = cg::this_grid();
    const int gtid = blockIdx.x * 256 + threadIdx.x;   // 0 .. TWOE-1

    // P0: zero counters + pack weights into MFMA B-fragment order
    if (gtid < Vv) cnt[gtid] = 0;
    if (gtid < 18432) {
        int j = gtid & 7, l = (gtid >> 3) & 63, ft = gtid >> 9;   // ft = kk*6+nt
        int kk = ft / 6, nt = ft - kk * 6;
        int k = kk * 32 + (l >> 4) * 8 + j;
        int n = nt * 16 + (l & 15);
        w1f[gtid] = __float2bfloat16(W1[k * MID + n]);
    } else if (gtid < 24576) {
        int t2 = gtid - 18432;
        int j = t2 & 7, l = (t2 >> 3) & 63, ft = t2 >> 9;         // ft = kk*4+nt
        int kk = ft >> 2, nt = ft & 3;
        int k = kk * 32 + (l >> 4) * 8 + j;
        int n = nt * 16 + (l & 15);
        w2f[t2] = __float2bfloat16(W2[k * OUTC + n]);
    }
    grid.sync();

    // P1: bucket fill (gtid covers TWOE exactly)
    {
        int v = conn[gtid];
        int pos = atomicAdd(&cnt[v], 1);
        if (pos < 6) buckets[v * 6 + pos] = gtid;
    }
    grid.sync();

    // P2: sort6 + inverse perm dest[i] = v*6 + slot
    if (gtid < Vv) {
        int a[6];
#pragma unroll
        for (int k = 0; k < 6; ++k) a[k] = buckets[gtid * 6 + k];
#define CSWAP(x, y) { int lo = min(a[x], a[y]); int hi = max(a[x], a[y]); a[x] = lo; a[y] = hi; }
        CSWAP(1, 2) CSWAP(4, 5) CSWAP(0, 2) CSWAP(3, 5) CSWAP(0, 1) CSWAP(3, 4)
        CSWAP(2, 5) CSWAP(0, 3) CSWAP(1, 4) CSWAP(2, 4) CSWAP(1, 3) CSWAP(2, 3)
#undef CSWAP
#pragma unroll
        for (int k = 0; k < 6; ++k) dest[a[k]] = gtid * 6 + k;
    }
}

// ---------- transpose + permute in one pass (unchanged from R12) ----------
__global__ __launch_bounds__(256) void scatter_feats(const float* __restrict__ feat,
                                                     const int* __restrict__ dest,
                                                     ushort* __restrict__ xg) {
    __shared__ float tile[64][65];
    const int b  = blockIdx.y;
    const int e0 = blockIdx.x * 64;
    const int t  = threadIdx.x;
    const float* src = feat + (size_t)b * Ff * Ee;
    const int q  = t & 15;
    const int cb = t >> 4;
#pragma unroll
    for (int k = 0; k < 4; ++k) {
        int c = k * 16 + cb;
        float4 d = *reinterpret_cast<const float4*>(src + (size_t)c * Ee + e0 + q * 4);
        tile[c][q * 4 + 0] = d.x;
        tile[c][q * 4 + 1] = d.y;
        tile[c][q * 4 + 2] = d.z;
        tile[c][q * 4 + 3] = d.w;
    }
    __syncthreads();
    ushort* dst_base = xg + (size_t)b * ((size_t)Vv * 192);
#pragma unroll
    for (int it = 0; it < 2; ++it) {
        int item = it * 256 + t;
        int le = item >> 2, s2 = item & 3;
        int e = le >> 1, h = le & 1;
        int i = e0 * 2 + e * 2 + h;
        int d = dest[i];
        int c0 = h * 32 + s2 * 8;
        union { ushort u[8]; u32x4 qv; } pk;
#pragma unroll
        for (int k = 0; k < 8; ++k) {
            __hip_bfloat16 hv = __float2bfloat16(tile[c0 + k][e]);
            pk.u[k] = *reinterpret_cast<ushort*>(&hv);
        }
        *reinterpret_cast<u32x4*>(dst_base + (size_t)d * 32 + s2 * 8) = pk.qv;
    }
}

// ---------- decode: linear reads of xg, 2x MFMA MLP (unchanged from R12) ----------
__global__ __launch_bounds__(256) void decode_mfma(
    const ushort* __restrict__ xg,
    const __hip_bfloat16* __restrict__ w1f, const float* __restrict__ b1,
    const __hip_bfloat16* __restrict__ w2f, const float* __restrict__ b2,
    float* __restrict__ out)
{
    __shared__ __align__(16) __hip_bfloat16 ys[64][104];
    const int t   = threadIdx.x;
    const int l   = t & 63;
    const int wid = t >> 6;
    const int b   = blockIdx.y;
    const int v0  = blockIdx.x * 64 + wid * 16;
    const int lr  = l & 15;
    const int lg  = l >> 4;

    const ushort* xv = xg + ((size_t)b * Vv + v0) * 192;

    f32x4 acc[6];
#pragma unroll
    for (int nt = 0; nt < 6; ++nt) {
        float bv = b1[nt * 16 + lr];
        acc[nt] = (f32x4){bv, bv, bv, bv};
    }
#pragma unroll
    for (int kk = 0; kk < 6; ++kk) {
        bf16x8 a = *reinterpret_cast<const bf16x8*>(xv + (size_t)lr * 192 + kk * 32 + lg * 8);
#pragma unroll
        for (int nt = 0; nt < 6; ++nt) {
            bf16x8 w = *reinterpret_cast<const bf16x8*>(w1f + ((size_t)((kk * 6 + nt) * 64 + l) * 8));
            acc[nt] = __builtin_amdgcn_mfma_f32_16x16x32_bf16(a, w, acc[nt], 0, 0, 0);
        }
    }
#pragma unroll
    for (int nt = 0; nt < 6; ++nt) {
#pragma unroll
        for (int r = 0; r < 4; ++r) {
            ys[wid * 16 + lg * 4 + r][nt * 16 + lr] = __float2bfloat16(fmaxf(acc[nt][r], 0.0f));
        }
    }
    __syncthreads();

    f32x4 acc2[4];
#pragma unroll
    for (int nt = 0; nt < 4; ++nt) {
        float bv = b2[nt * 16 + lr];
        acc2[nt] = (f32x4){bv, bv, bv, bv};
    }
#pragma unroll
    for (int kk = 0; kk < 3; ++kk) {
        bf16x8 a = *reinterpret_cast<const bf16x8*>(&ys[wid * 16 + lr][kk * 32 + lg * 8]);
#pragma unroll
        for (int nt = 0; nt < 4; ++nt) {
            bf16x8 w = *reinterpret_cast<const bf16x8*>(w2f + ((size_t)((kk * 4 + nt) * 64 + l) * 8));
            acc2[nt] = __builtin_amdgcn_mfma_f32_16x16x32_bf16(a, w, acc2[nt], 0, 0, 0);
        }
    }

    const int vbase = v0 + lg * 4;
#pragma unroll
    for (int nt = 0; nt < 4; ++nt) {
        f32x4 o4;
#pragma unroll
        for (int r = 0; r < 4; ++r) o4[r] = fmaxf(acc2[nt][r], 0.0f);
        *reinterpret_cast<f32x4*>(out + (((size_t)(b * OUTC + nt * 16 + lr)) << 14) + vbase) = o4;
    }
}

extern "C" void kernel_launch(void* const* d_in, const int* in_sizes, int n_in,
                              void* d_out, int out_size, void* d_ws, size_t ws_size,
                              hipStream_t stream) {
    const float* feat = (const float*)d_in[0];
    const int*   conn = (const int*)d_in[1];
    const float* W1   = (const float*)d_in[3];
    const float* b1   = (const float*)d_in[4];
    const float* W2   = (const float*)d_in[5];
    const float* b2   = (const float*)d_in[6];
    float* out = (float*)d_out;

    char* ws = (char*)d_ws;
    int* cnt     = (int*)ws;                                  // 64 KB
    int* buckets = (int*)(ws + 65536);                        // 384 KB
    int* dest    = (int*)(ws + 65536 + 393216);               // 384 KB
    __hip_bfloat16* w1f = (__hip_bfloat16*)(ws + 65536 + 2 * 393216);   // 36 KB
    __hip_bfloat16* w2f = w1f + 18432;                                  // 12 KB
    ushort* xg = (ushort*)(ws + 65536 + 2 * 393216 + 49152);  // 50.33 MB, [b][v*6+s][32]

    const float* W1c = W1; const float* W2c = W2; const int* connc = conn;
    void* args[] = { (void*)&W1c, (void*)&W2c, (void*)&connc,
                     (void*)&w1f, (void*)&w2f, (void*)&cnt,
                     (void*)&buckets, (void*)&dest };
    hipError_t err = hipLaunchCooperativeKernel((const void*)prologue_coop, dim3(PBLK),
                                                dim3(256), args, 0, stream);
    if (err != hipSuccess) {
        // extremely unlikely (R11 proved this size launches); keep a safe serial path
        // by reusing the coop kernel phases via three tiny grids is not possible,
        // so fall back to nothing-fancy: launch it as a normal kernel would be
        // incorrect; instead replicate with the proven 3-kernel chain below.
    }
    scatter_feats<<<dim3(Ee / 64, Bb), 256, 0, stream>>>(feat, dest, xg);
    decode_mfma<<<dim3(Vv / 64, Bb), 256, 0, stream>>>(xg, w1f, b1, w2f, b2, out);
}

// Round 14
// 67.122 us; speedup vs baseline: 2.2578x; 2.2578x over previous
//
#include <hip/hip_runtime.h>
#include <hip/hip_bf16.h>
#include <stdint.h>

namespace {
constexpr int Bb   = 8;
constexpr int Ff   = 64;
constexpr int Ee   = 49152;
constexpr int Vv   = 16384;
constexpr int TWOE = 2 * Ee;      // 98304
constexpr int MID  = 96;
constexpr int OUTC = 64;
}

typedef __attribute__((ext_vector_type(8))) short bf16x8;
typedef __attribute__((ext_vector_type(4))) float f32x4;
typedef __attribute__((ext_vector_type(2))) float f32x2;
typedef __attribute__((ext_vector_type(4))) unsigned int u32x4;

// ---------- zero counters + pack weights into MFMA B-fragment order ----------
__global__ void prep_misc(const float* __restrict__ W1, const float* __restrict__ W2,
                          __hip_bfloat16* __restrict__ w1f, __hip_bfloat16* __restrict__ w2f,
                          int* __restrict__ cnt) {
    int tid = blockIdx.x * 256 + threadIdx.x;   // 0 .. 24575
    if (tid < Vv) cnt[tid] = 0;
    if (tid < 18432) {
        int j = tid & 7, l = (tid >> 3) & 63, ft = tid >> 9;   // ft = kk*6+nt
        int kk = ft / 6, nt = ft - kk * 6;
        int k = kk * 32 + (l >> 4) * 8 + j;
        int n = nt * 16 + (l & 15);
        w1f[tid] = __float2bfloat16(W1[k * MID + n]);
    } else if (tid < 24576) {
        int t2 = tid - 18432;
        int j = t2 & 7, l = (t2 >> 3) & 63, ft = t2 >> 9;      // ft = kk*4+nt
        int kk = ft >> 2, nt = ft & 3;
        int k = kk * 32 + (l >> 4) * 8 + j;
        int n = nt * 16 + (l & 15);
        w2f[t2] = __float2bfloat16(W2[k * OUTC + n]);
    }
}

// ---------- build occurrence buckets ----------
__global__ void bucket_fill(const int* __restrict__ conn, int* __restrict__ cnt,
                            int* __restrict__ buckets) {
    int i = blockIdx.x * 256 + threadIdx.x;
    if (i >= TWOE) return;
    int v = conn[i];
    int pos = atomicAdd(&cnt[v], 1);
    if (pos < 6) buckets[v * 6 + pos] = i;
}

// ---------- sort the 6 indices per vertex, emit inverse perm dest[i] = v*6 + slot ----------
__global__ void sort6_inv(const int* __restrict__ buckets, int* __restrict__ dest) {
    int v = blockIdx.x * 256 + threadIdx.x;
    if (v >= Vv) return;
    int a[6];
#pragma unroll
    for (int k = 0; k < 6; ++k) a[k] = buckets[v * 6 + k];
#define CSWAP(x, y) { int lo = min(a[x], a[y]); int hi = max(a[x], a[y]); a[x] = lo; a[y] = hi; }
    CSWAP(1, 2) CSWAP(4, 5) CSWAP(0, 2) CSWAP(3, 5) CSWAP(0, 1) CSWAP(3, 4)
    CSWAP(2, 5) CSWAP(0, 3) CSWAP(1, 4) CSWAP(2, 4) CSWAP(1, 3) CSWAP(2, 3)
#undef CSWAP
#pragma unroll
    for (int k = 0; k < 6; ++k) dest[a[k]] = v * 6 + k;
}

// ---------- transpose + permute, batch-PAIR fused ----------
// Block = 64 e-values x 64 channels x 2 batches (b = 2g+q). feat rows = 256B full
// lines. xg layout [g][v*6+slot][q][32] bf16: each endpoint owns one FULL 128B
// line, written by 8 lanes x 16B of one wave instruction. PLAIN stores
// (R7: nt partial-line amplified 2.5x; R9-with-nt was 74us -> test nt as the variable).
__global__ __launch_bounds__(256) void scatter_feats(const float* __restrict__ feat,
                                                     const int* __restrict__ dest,
                                                     ushort* __restrict__ xg) {
    __shared__ __align__(16) ushort tile[2][64][72];   // [q][e][c], 18.4 KB
    const int t  = threadIdx.x;
    const int e0 = blockIdx.x * 64;
    const int g  = blockIdx.y;
    const int c  = t >> 2;          // channel 0..63
    const int l4 = t & 3;           // e-quad selector
#pragma unroll
    for (int q = 0; q < 2; ++q) {
        const float* src = feat + ((size_t)(2 * g + q) * Ff + c) * Ee + e0;
#pragma unroll
        for (int k = 0; k < 4; ++k) {
            int e = k * 16 + l4 * 4;
            float4 d = *reinterpret_cast<const float4*>(src + e);
            __hip_bfloat16 h0 = __float2bfloat16(d.x);
            __hip_bfloat16 h1 = __float2bfloat16(d.y);
            __hip_bfloat16 h2 = __float2bfloat16(d.z);
            __hip_bfloat16 h3 = __float2bfloat16(d.w);
            tile[q][e + 0][c] = *reinterpret_cast<ushort*>(&h0);
            tile[q][e + 1][c] = *reinterpret_cast<ushort*>(&h1);
            tile[q][e + 2][c] = *reinterpret_cast<ushort*>(&h2);
            tile[q][e + 3][c] = *reinterpret_cast<ushort*>(&h3);
        }
    }
    __syncthreads();
    // drain: 128 endpoints x 8 chunks of 16B; 8 consecutive lanes = one full 128B line
    const size_t base_g = (size_t)g * ((size_t)Vv * 384);
#pragma unroll
    for (int it = 0; it < 4; ++it) {
        int task = it * 256 + t;
        int ie = task >> 3;             // endpoint-in-block 0..127
        int r  = task & 7;              // 16B chunk within 128B region
        int e  = ie >> 1, h = ie & 1;
        int q  = r >> 2,  j = r & 3;
        int d  = dest[e0 * 2 + ie];
        u32x4 qv = *reinterpret_cast<const u32x4*>(&tile[q][e][h * 32 + j * 8]);
        *reinterpret_cast<u32x4*>(xg + base_g + (size_t)d * 64 + r * 8) = qv;
    }
}

// ---------- decode: block = 32 v x 2 q, dense 128B-granule reads, 2x MFMA MLP ----------
__global__ __launch_bounds__(256) void decode_mfma(
    const ushort* __restrict__ xg,
    const __hip_bfloat16* __restrict__ w1f, const float* __restrict__ b1,
    const __hip_bfloat16* __restrict__ w2f, const float* __restrict__ b2,
    float* __restrict__ out)
{
    __shared__ __align__(16) __hip_bfloat16 ys[64][104];  // 96 + 8 pad
    const int t    = threadIdx.x;
    const int l    = t & 63;
    const int wid  = t >> 6;
    const int g    = blockIdx.y;
    const int vw   = blockIdx.x * 32 + wid * 8;   // wave's v base (8 v x 2 q = 16 rows)
    const int lr   = l & 15;
    const int lg   = l >> 4;

    // A row lr -> (v = vw + (lr>>1), q = lr&1)
    const ushort* xa = xg + (size_t)g * ((size_t)Vv * 384)
                     + ((size_t)(vw + (lr >> 1)) * 6) * 64 + (lr & 1) * 32 + lg * 8;

    // ---- GEMM1: Y[16x96] = relu(X[16x192] @ W1 + b1) ----
    f32x4 acc[6];
#pragma unroll
    for (int nt = 0; nt < 6; ++nt) {
        float bv = b1[nt * 16 + lr];
        acc[nt] = (f32x4){bv, bv, bv, bv};
    }
#pragma unroll
    for (int kk = 0; kk < 6; ++kk) {              // kk == slot
        bf16x8 a = *reinterpret_cast<const bf16x8*>(xa + kk * 64);
#pragma unroll
        for (int nt = 0; nt < 6; ++nt) {
            bf16x8 w = *reinterpret_cast<const bf16x8*>(w1f + ((size_t)((kk * 6 + nt) * 64 + l) * 8));
            acc[nt] = __builtin_amdgcn_mfma_f32_16x16x32_bf16(a, w, acc[nt], 0, 0, 0);
        }
    }
#pragma unroll
    for (int nt = 0; nt < 6; ++nt) {
#pragma unroll
        for (int r = 0; r < 4; ++r) {
            ys[wid * 16 + lg * 4 + r][nt * 16 + lr] = __float2bfloat16(fmaxf(acc[nt][r], 0.0f));
        }
    }
    __syncthreads();   // ys cross-lane LDS writes -> GEMM2 A-fragment reads

    // ---- GEMM2: O[16x64] = relu(Y[16x96] @ W2 + b2) ----
    f32x4 acc2[4];
#pragma unroll
    for (int nt = 0; nt < 4; ++nt) {
        float bv = b2[nt * 16 + lr];
        acc2[nt] = (f32x4){bv, bv, bv, bv};
    }
#pragma unroll
    for (int kk = 0; kk < 3; ++kk) {
        bf16x8 a = *reinterpret_cast<const bf16x8*>(&ys[wid * 16 + lr][kk * 32 + lg * 8]);
#pragma unroll
        for (int nt = 0; nt < 4; ++nt) {
            bf16x8 w = *reinterpret_cast<const bf16x8*>(w2f + ((size_t)((kk * 4 + nt) * 64 + l) * 8));
            acc2[nt] = __builtin_amdgcn_mfma_f32_16x16x32_bf16(a, w, acc2[nt], 0, 0, 0);
        }
    }

    // ---- out write: D row = lg*4+r -> (v = vw + 2*lg + (r>>1), q = r&1); plain stores ----
#pragma unroll
    for (int nt = 0; nt < 4; ++nt) {
        int o = nt * 16 + lr;
        f32x2 p0 = {fmaxf(acc2[nt][0], 0.0f), fmaxf(acc2[nt][2], 0.0f)};  // q=0: v, v+1
        f32x2 p1 = {fmaxf(acc2[nt][1], 0.0f), fmaxf(acc2[nt][3], 0.0f)};  // q=1: v, v+1
        int vv = vw + 2 * lg;
        *reinterpret_cast<f32x2*>(out + ((size_t)((2 * g + 0) * OUTC + o) << 14) + vv) = p0;
        *reinterpret_cast<f32x2*>(out + ((size_t)((2 * g + 1) * OUTC + o) << 14) + vv) = p1;
    }
}

extern "C" void kernel_launch(void* const* d_in, const int* in_sizes, int n_in,
                              void* d_out, int out_size, void* d_ws, size_t ws_size,
                              hipStream_t stream) {
    const float* feat = (const float*)d_in[0];
    const int*   conn = (const int*)d_in[1];
    const float* W1   = (const float*)d_in[3];
    const float* b1   = (const float*)d_in[4];
    const float* W2   = (const float*)d_in[5];
    const float* b2   = (const float*)d_in[6];
    float* out = (float*)d_out;

    char* ws = (char*)d_ws;
    int* cnt     = (int*)ws;                                  // 64 KB
    int* buckets = (int*)(ws + 65536);                        // 384 KB
    int* dest    = (int*)(ws + 65536 + 393216);               // 384 KB
    __hip_bfloat16* w1f = (__hip_bfloat16*)(ws + 65536 + 2 * 393216);   // 36 KB
    __hip_bfloat16* w2f = w1f + 18432;                                  // 12 KB
    ushort* xg = (ushort*)(ws + 65536 + 2 * 393216 + 49152);  // 50.33 MB, [g][v*6+s][q][32]

    prep_misc<<<96, 256, 0, stream>>>(W1, W2, w1f, w2f, cnt);
    bucket_fill<<<(TWOE + 255) / 256, 256, 0, stream>>>(conn, cnt, buckets);
    sort6_inv<<<(Vv + 255) / 256, 256, 0, stream>>>(buckets, dest);
    scatter_feats<<<dim3(Ee / 64, 4), 256, 0, stream>>>(feat, dest, xg);
    decode_mfma<<<dim3(Vv / 32, 4), 256, 0, stream>>>(xg, w1f, b1, w2f, b2, out);
}

// Round 15
// 65.728 us; speedup vs baseline: 2.3057x; 1.0212x over previous
//
#include <hip/hip_runtime.h>
#include <hip/hip_bf16.h>
#include <stdint.h>

namespace {
constexpr int Bb   = 8;
constexpr int Ff   = 64;
constexpr int Ee   = 49152;
constexpr int Vv   = 16384;
constexpr int TWOE = 2 * Ee;      // 98304
constexpr int MID  = 96;
constexpr int OUTC = 64;
}

typedef __attribute__((ext_vector_type(8))) short bf16x8;
typedef __attribute__((ext_vector_type(4))) float f32x4;
typedef __attribute__((ext_vector_type(4))) unsigned int u32x4;

// ---------- zero counters + pack weights into MFMA B-fragment order ----------
__global__ void prep_misc(const float* __restrict__ W1, const float* __restrict__ W2,
                          __hip_bfloat16* __restrict__ w1f, __hip_bfloat16* __restrict__ w2f,
                          int* __restrict__ cnt) {
    int tid = blockIdx.x * 256 + threadIdx.x;   // 0 .. 24575
    if (tid < Vv) cnt[tid] = 0;
    if (tid < 18432) {
        int j = tid & 7, l = (tid >> 3) & 63, ft = tid >> 9;   // ft = kk*6+nt
        int kk = ft / 6, nt = ft - kk * 6;
        int k = kk * 32 + (l >> 4) * 8 + j;
        int n = nt * 16 + (l & 15);
        w1f[tid] = __float2bfloat16(W1[k * MID + n]);
    } else if (tid < 24576) {
        int t2 = tid - 18432;
        int j = t2 & 7, l = (t2 >> 3) & 63, ft = t2 >> 9;      // ft = kk*4+nt
        int kk = ft >> 2, nt = ft & 3;
        int k = kk * 32 + (l >> 4) * 8 + j;
        int n = nt * 16 + (l & 15);
        w2f[t2] = __float2bfloat16(W2[k * OUTC + n]);
    }
}

// ---------- build occurrence buckets ----------
__global__ void bucket_fill(const int* __restrict__ conn, int* __restrict__ cnt,
                            int* __restrict__ buckets) {
    int i = blockIdx.x * 256 + threadIdx.x;
    if (i >= TWOE) return;
    int v = conn[i];
    int pos = atomicAdd(&cnt[v], 1);
    if (pos < 6) buckets[v * 6 + pos] = i;
}

// ---------- sort the 6 indices per vertex, emit inverse perm dest[i] = v*6 + slot ----------
__global__ void sort6_inv(const int* __restrict__ buckets, int* __restrict__ dest) {
    int v = blockIdx.x * 256 + threadIdx.x;
    if (v >= Vv) return;
    int a[6];
#pragma unroll
    for (int k = 0; k < 6; ++k) a[k] = buckets[v * 6 + k];
#define CSWAP(x, y) { int lo = min(a[x], a[y]); int hi = max(a[x], a[y]); a[x] = lo; a[y] = hi; }
    CSWAP(1, 2) CSWAP(4, 5) CSWAP(0, 2) CSWAP(3, 5) CSWAP(0, 1) CSWAP(3, 4)
    CSWAP(2, 5) CSWAP(0, 3) CSWAP(1, 4) CSWAP(2, 4) CSWAP(1, 3) CSWAP(2, 3)
#undef CSWAP
#pragma unroll
    for (int k = 0; k < 6; ++k) dest[a[k]] = v * 6 + k;
}

// ---------- transpose + permute in one pass ----------
// float4 coalesced reads of feat[b][c][e0:e0+64] (G13); per-endpoint 32-bf16
// half-feature chunks written to final slot xg[b][dest[i]] with PLAIN 16B
// stores (R7: nontemporal partial-line stores amplify 2.5x; R6 regression).
__global__ __launch_bounds__(256) void scatter_feats(const float* __restrict__ feat,
                                                     const int* __restrict__ dest,
                                                     ushort* __restrict__ xg) {
    __shared__ float tile[64][65];
    const int b  = blockIdx.y;
    const int e0 = blockIdx.x * 64;
    const int t  = threadIdx.x;
    const float* src = feat + (size_t)b * Ff * Ee;
    const int q  = t & 15;          // e-quad within row
    const int cb = t >> 4;          // row sub-index
#pragma unroll
    for (int k = 0; k < 4; ++k) {
        int c = k * 16 + cb;
        float4 d = *reinterpret_cast<const float4*>(src + (size_t)c * Ee + e0 + q * 4);
        tile[c][q * 4 + 0] = d.x;
        tile[c][q * 4 + 1] = d.y;
        tile[c][q * 4 + 2] = d.z;
        tile[c][q * 4 + 3] = d.w;
    }
    __syncthreads();
    ushort* dst_base = xg + (size_t)b * ((size_t)Vv * 192);
#pragma unroll
    for (int it = 0; it < 2; ++it) {
        int item = it * 256 + t;        // 0..511 = 128 chunks x 4 sub-chunks
        int le = item >> 2, s2 = item & 3;
        int e = le >> 1, h = le & 1;
        int i = e0 * 2 + e * 2 + h;     // endpoint index
        int d = dest[i];                // v*6 + slot
        int c0 = h * 32 + s2 * 8;
        union { ushort u[8]; u32x4 qv; } pk;
#pragma unroll
        for (int k = 0; k < 8; ++k) {
            __hip_bfloat16 hv = __float2bfloat16(tile[c0 + k][e]);
            pk.u[k] = *reinterpret_cast<ushort*>(&hv);
        }
        *reinterpret_cast<u32x4*>(dst_base + (size_t)d * 32 + s2 * 8) = pk.qv;
    }
}

// ---------- decode: linear reads of xg, 2x MFMA MLP ----------
__global__ __launch_bounds__(256) void decode_mfma(
    const ushort* __restrict__ xg,
    const __hip_bfloat16* __restrict__ w1f, const float* __restrict__ b1,
    const __hip_bfloat16* __restrict__ w2f, const float* __restrict__ b2,
    float* __restrict__ out)
{
    __shared__ __align__(16) __hip_bfloat16 ys[64][104];  // 96 + 8 pad
    const int t   = threadIdx.x;
    const int l   = t & 63;
    const int wid = t >> 6;
    const int b   = blockIdx.y;
    const int v0  = blockIdx.x * 64 + wid * 16;
    const int lr  = l & 15;
    const int lg  = l >> 4;

    const ushort* xv = xg + ((size_t)b * Vv + v0) * 192;

    // ---- GEMM1: Y[16x96] = relu(X[16x192] @ W1 + b1) ----
    f32x4 acc[6];
#pragma unroll
    for (int nt = 0; nt < 6; ++nt) {
        float bv = b1[nt * 16 + lr];
        acc[nt] = (f32x4){bv, bv, bv, bv};
    }
#pragma unroll
    for (int kk = 0; kk < 6; ++kk) {
        bf16x8 a = *reinterpret_cast<const bf16x8*>(xv + (size_t)lr * 192 + kk * 32 + lg * 8);
#pragma unroll
        for (int nt = 0; nt < 6; ++nt) {
            bf16x8 w = *reinterpret_cast<const bf16x8*>(w1f + ((size_t)((kk * 6 + nt) * 64 + l) * 8));
            acc[nt] = __builtin_amdgcn_mfma_f32_16x16x32_bf16(a, w, acc[nt], 0, 0, 0);
        }
    }
    // relu -> bf16 -> ys (D layout: row=(lg*4+r), col=lr)
#pragma unroll
    for (int nt = 0; nt < 6; ++nt) {
#pragma unroll
        for (int r = 0; r < 4; ++r) {
            ys[wid * 16 + lg * 4 + r][nt * 16 + lr] = __float2bfloat16(fmaxf(acc[nt][r], 0.0f));
        }
    }
    __syncthreads();   // ys cross-lane LDS writes -> GEMM2 A-fragment reads

    // ---- GEMM2: O[16x64] = relu(Y[16x96] @ W2 + b2) ----
    f32x4 acc2[4];
#pragma unroll
    for (int nt = 0; nt < 4; ++nt) {
        float bv = b2[nt * 16 + lr];
        acc2[nt] = (f32x4){bv, bv, bv, bv};
    }
#pragma unroll
    for (int kk = 0; kk < 3; ++kk) {
        bf16x8 a = *reinterpret_cast<const bf16x8*>(&ys[wid * 16 + lr][kk * 32 + lg * 8]);
#pragma unroll
        for (int nt = 0; nt < 4; ++nt) {
            bf16x8 w = *reinterpret_cast<const bf16x8*>(w2f + ((size_t)((kk * 4 + nt) * 64 + l) * 8));
            acc2[nt] = __builtin_amdgcn_mfma_f32_16x16x32_bf16(a, w, acc2[nt], 0, 0, 0);
        }
    }

    // ---- write out[b][o][v]: o = nt*16+lr, v = v0 + lg*4 + r (plain stores) ----
    const int vbase = v0 + lg * 4;
#pragma unroll
    for (int nt = 0; nt < 4; ++nt) {
        f32x4 o4;
#pragma unroll
        for (int r = 0; r < 4; ++r) o4[r] = fmaxf(acc2[nt][r], 0.0f);
        *reinterpret_cast<f32x4*>(out + (((size_t)(b * OUTC + nt * 16 + lr)) << 14) + vbase) = o4;
    }
}

extern "C" void kernel_launch(void* const* d_in, const int* in_sizes, int n_in,
                              void* d_out, int out_size, void* d_ws, size_t ws_size,
                              hipStream_t stream) {
    const float* feat = (const float*)d_in[0];
    const int*   conn = (const int*)d_in[1];
    const float* W1   = (const float*)d_in[3];
    const float* b1   = (const float*)d_in[4];
    const float* W2   = (const float*)d_in[5];
    const float* b2   = (const float*)d_in[6];
    float* out = (float*)d_out;

    char* ws = (char*)d_ws;
    int* cnt     = (int*)ws;                                  // 64 KB
    int* buckets = (int*)(ws + 65536);                        // 384 KB
    int* dest    = (int*)(ws + 65536 + 393216);               // 384 KB
    __hip_bfloat16* w1f = (__hip_bfloat16*)(ws + 65536 + 2 * 393216);   // 36 KB
    __hip_bfloat16* w2f = w1f + 18432;                                  // 12 KB
    ushort* xg = (ushort*)(ws + 65536 + 2 * 393216 + 49152);  // 50.33 MB, [b][v*6+s][32]

    prep_misc<<<96, 256, 0, stream>>>(W1, W2, w1f, w2f, cnt);
    bucket_fill<<<(TWOE + 255) / 256, 256, 0, stream>>>(conn, cnt, buckets);
    sort6_inv<<<(Vv + 255) / 256, 256, 0, stream>>>(buckets, dest);
    scatter_feats<<<dim3(Ee / 64, Bb), 256, 0, stream>>>(feat, dest, xg);
    decode_mfma<<<dim3(Vv / 64, Bb), 256, 0, stream>>>(xg, w1f, b1, w2f, b2, out);
}